// Round 1
// baseline (437.457 us; speedup 1.0000x reference)
//
#include <hip/hip_runtime.h>
#include <hip/hip_bf16.h>
#include <stdint.h>

#define DEV __device__ __forceinline__

typedef __attribute__((ext_vector_type(8))) __bf16 bf16x8;
typedef __attribute__((ext_vector_type(4))) float f32x4;
typedef __attribute__((ext_vector_type(4))) unsigned int u32x4;

DEV unsigned short f2bf(float f) {
    union { float f; unsigned int u; } v; v.f = f;
    unsigned int u = v.u;
    return (unsigned short)((u + 0x7FFFu + ((u >> 16) & 1u)) >> 16);
}

DEV f32x4 mfma16(bf16x8 a, bf16x8 b, f32x4 c) {
    return __builtin_amdgcn_mfma_f32_16x16x32_bf16(a, b, c, 0, 0, 0);
}

#define GLOAD_LDS16(g, l)                                                          \
    __builtin_amdgcn_global_load_lds((__attribute__((address_space(1))) void*)(g), \
                                     (__attribute__((address_space(3))) void*)(l), \
                                     16, 0, 0)

// ---------------- f32 -> bf16 convert ----------------
__global__ void k_cvt(const float* __restrict__ in, unsigned short* __restrict__ out, int n) {
    int stride = gridDim.x * blockDim.x;
    for (int i = blockIdx.x * blockDim.x + threadIdx.x; i * 4 < n; i += stride) {
        float4 f = reinterpret_cast<const float4*>(in)[i];
        ushort4 o;
        o.x = f2bf(f.x); o.y = f2bf(f.y); o.z = f2bf(f.z); o.w = f2bf(f.w);
        reinterpret_cast<ushort4*>(out)[i] = o;
    }
}

// ---------------- bias_k = -0.5 * sum_d k^2 ----------------
__global__ void k_rowsq(const unsigned short* __restrict__ Kp, float* __restrict__ biask, int nrows) {
    int r = blockIdx.x * blockDim.x + threadIdx.x;
    if (r >= nrows) return;
    const unsigned short* p = Kp + (size_t)r * 64;
    float s = 0.f;
#pragma unroll
    for (int i = 0; i < 8; ++i) {
        u32x4 u = reinterpret_cast<const u32x4*>(p)[i];
        bf16x8 h = __builtin_bit_cast(bf16x8, u);
#pragma unroll
        for (int j = 0; j < 8; ++j) { float f = (float)h[j]; s += f * f; }
    }
    biask[r] = -0.5f * s;
}

// ---------------- GEMM: C = A(MxK) * Bw(NxK)^T + bias ----------------
// MODE 0: out bf16 written to (B,H,L,D) layout (for QKV projections)
// MODE 1: out f32 row-major MxN (final projection)
template <int MODE>
__global__ __launch_bounds__(256) void k_gemm(const unsigned short* __restrict__ A,
                                              const unsigned short* __restrict__ Bw,
                                              const float* __restrict__ bias,
                                              void* __restrict__ out,
                                              int M, int N, int K) {
    __shared__ __align__(16) unsigned short As[128 * 64];
    __shared__ __align__(16) unsigned short Bs[128 * 64];
    const int tid = threadIdx.x;
    const int lane = tid & 63, w = tid >> 6;
    const int g = lane >> 4, cc = lane & 15;
    const int wm = w >> 1, wn = w & 1;
    const int bm = blockIdx.y, bn = blockIdx.x;

    f32x4 acc[4][4] = {};
    const int srow = lane >> 3;        // 0..7
    const int scol = (lane & 7) * 8;   // 0..56

    for (int kt = 0; kt < K; kt += 64) {
#pragma unroll
        for (int p = 0; p < 4; ++p) {
            int c = w * 4 + p;                 // chunk 0..15, rows c*8..c*8+7
            int row = c * 8 + srow;
            const unsigned short* gA = A + (size_t)(bm * 128 + row) * K + kt + scol;
            GLOAD_LDS16(gA, &As[c * 512]);
            const unsigned short* gB = Bw + (size_t)(bn * 128 + row) * K + kt + scol;
            GLOAD_LDS16(gB, &Bs[c * 512]);
        }
        __syncthreads();
#pragma unroll
        for (int kc = 0; kc < 2; ++kc) {
            bf16x8 af[4], bf[4];
#pragma unroll
            for (int i = 0; i < 4; ++i) {
                af[i] = *reinterpret_cast<const bf16x8*>(&As[(wm * 64 + i * 16 + cc) * 64 + kc * 32 + g * 8]);
                bf[i] = *reinterpret_cast<const bf16x8*>(&Bs[(wn * 64 + i * 16 + cc) * 64 + kc * 32 + g * 8]);
            }
#pragma unroll
            for (int mi = 0; mi < 4; ++mi)
#pragma unroll
                for (int nj = 0; nj < 4; ++nj)
                    acc[mi][nj] = mfma16(af[mi], bf[nj], acc[mi][nj]);
        }
        __syncthreads();
    }

#pragma unroll
    for (int mi = 0; mi < 4; ++mi) {
#pragma unroll
        for (int nj = 0; nj < 4; ++nj) {
            int n = bn * 128 + wn * 64 + nj * 16 + cc;
            float bv = bias[n];
#pragma unroll
            for (int r = 0; r < 4; ++r) {
                int m = bm * 128 + wm * 64 + mi * 16 + g * 4 + r;
                float vv = acc[mi][nj][r] + bv;
                if (MODE == 0) {
                    int b = m >> 11, l = m & 2047, h = n >> 6, d = n & 63;
                    ((unsigned short*)out)[(((size_t)b * 16 + h) * 2048 + l) * 64 + d] = f2bf(vv);
                } else {
                    ((float*)out)[(size_t)m * N + n] = vv;
                }
            }
        }
    }
}

// ---------------- flash attention with per-key bias ----------------
// Q,K,V: (B*H, L, 64) bf16.  biask: (B*H*L) f32 = -0.5*||k||^2.
// Ob: (B, L, H*64) bf16.
__global__ __launch_bounds__(256) void k_attn(const unsigned short* __restrict__ Q,
                                              const unsigned short* __restrict__ Kp,
                                              const unsigned short* __restrict__ Vp,
                                              const float* __restrict__ biask,
                                              unsigned short* __restrict__ Ob) {
    __shared__ __align__(16) unsigned short Kt[64 * 72];
    __shared__ __align__(16) unsigned short Vt[64 * 72];   // transposed: [d][k]
    __shared__ __align__(16) unsigned short Pl[4][32 * 72];

    const int tid = threadIdx.x;
    const int lane = tid & 63, w = tid >> 6;
    const int g = lane >> 4, cc = lane & 15;
    const int bh = blockIdx.y, qt = blockIdx.x;
    const size_t base = (size_t)bh * 2048 * 64;
    const int q0 = qt * 128 + w * 32;

    // Q fragments (A-layout): row = lane&15 (+16*mi), k = kc*32 + g*8
    bf16x8 aq[2][2];
#pragma unroll
    for (int mi = 0; mi < 2; ++mi)
#pragma unroll
        for (int kc = 0; kc < 2; ++kc) {
            const unsigned short* p = Q + base + (size_t)(q0 + mi * 16 + cc) * 64 + kc * 32 + g * 8;
            aq[mi][kc] = __builtin_bit_cast(bf16x8, *reinterpret_cast<const u32x4*>(p));
        }

    float mrun[2][4], lrun[2][4];
    f32x4 o[2][4] = {};
#pragma unroll
    for (int mi = 0; mi < 2; ++mi)
#pragma unroll
        for (int r = 0; r < 4; ++r) { mrun[mi][r] = -1e30f; lrun[mi][r] = 0.f; }

    const int kr = tid >> 2;          // 0..63
    const int kcol = (tid & 3) * 16;  // 0/16/32/48

    for (int t = 0; t < 32; ++t) {
        // stage K (natural, padded) and V (transposed)
        const unsigned short* gK = Kp + base + (size_t)(t * 64 + kr) * 64 + kcol;
        const unsigned short* gV = Vp + base + (size_t)(t * 64 + kr) * 64 + kcol;
#pragma unroll
        for (int i = 0; i < 2; ++i) {
            u32x4 uk = *reinterpret_cast<const u32x4*>(gK + i * 8);
            *reinterpret_cast<u32x4*>(&Kt[kr * 72 + kcol + i * 8]) = uk;
            union { u32x4 v; unsigned short s[8]; } uv;
            uv.v = *reinterpret_cast<const u32x4*>(gV + i * 8);
#pragma unroll
            for (int j = 0; j < 8; ++j) Vt[(kcol + i * 8 + j) * 72 + kr] = uv.s[j];
        }
        __syncthreads();

        // S = Q K^T  (C-layout: row=g*4+r (+16mi), col=cc (+16nj))
        f32x4 s[2][4] = {};
#pragma unroll
        for (int kc = 0; kc < 2; ++kc) {
#pragma unroll
            for (int nj = 0; nj < 4; ++nj) {
                bf16x8 bk = *reinterpret_cast<const bf16x8*>(&Kt[(nj * 16 + cc) * 72 + kc * 32 + g * 8]);
                s[0][nj] = mfma16(aq[0][kc], bk, s[0][nj]);
                s[1][nj] = mfma16(aq[1][kc], bk, s[1][nj]);
            }
        }
        float bb[4];
#pragma unroll
        for (int nj = 0; nj < 4; ++nj) bb[nj] = biask[bh * 2048 + t * 64 + nj * 16 + cc];
#pragma unroll
        for (int mi = 0; mi < 2; ++mi)
#pragma unroll
            for (int nj = 0; nj < 4; ++nj)
#pragma unroll
                for (int r = 0; r < 4; ++r) s[mi][nj][r] += bb[nj];

        // online softmax per row (mi,r); row-reduce = 4 local + shfl_xor{1,2,4,8}
#pragma unroll
        for (int mi = 0; mi < 2; ++mi)
#pragma unroll
            for (int r = 0; r < 4; ++r) {
                float mx = fmaxf(fmaxf(s[mi][0][r], s[mi][1][r]), fmaxf(s[mi][2][r], s[mi][3][r]));
                mx = fmaxf(mx, __shfl_xor(mx, 1));
                mx = fmaxf(mx, __shfl_xor(mx, 2));
                mx = fmaxf(mx, __shfl_xor(mx, 4));
                mx = fmaxf(mx, __shfl_xor(mx, 8));
                float mo = mrun[mi][r];
                float mn = fmaxf(mo, mx);
                float sc = __expf(mo - mn);
                float rs = 0.f;
#pragma unroll
                for (int nj = 0; nj < 4; ++nj) {
                    float pv = __expf(s[mi][nj][r] - mn);
                    s[mi][nj][r] = pv;
                    rs += pv;
                }
                rs += __shfl_xor(rs, 1);
                rs += __shfl_xor(rs, 2);
                rs += __shfl_xor(rs, 4);
                rs += __shfl_xor(rs, 8);
                lrun[mi][r] = lrun[mi][r] * sc + rs;
                mrun[mi][r] = mn;
#pragma unroll
                for (int dj = 0; dj < 4; ++dj) o[mi][dj][r] *= sc;
            }

        // P (C-layout) -> per-wave LDS (row-major, padded)
#pragma unroll
        for (int mi = 0; mi < 2; ++mi)
#pragma unroll
            for (int nj = 0; nj < 4; ++nj)
#pragma unroll
                for (int r = 0; r < 4; ++r)
                    Pl[w][(mi * 16 + g * 4 + r) * 72 + nj * 16 + cc] = f2bf(s[mi][nj][r]);

        // O += P V   (A = P from LDS, B = V^T rows, both ds_read_b128)
#pragma unroll
        for (int kc = 0; kc < 2; ++kc) {
            bf16x8 ap0 = *reinterpret_cast<const bf16x8*>(&Pl[w][(cc) * 72 + kc * 32 + g * 8]);
            bf16x8 ap1 = *reinterpret_cast<const bf16x8*>(&Pl[w][(16 + cc) * 72 + kc * 32 + g * 8]);
#pragma unroll
            for (int dj = 0; dj < 4; ++dj) {
                bf16x8 bv = *reinterpret_cast<const bf16x8*>(&Vt[(dj * 16 + cc) * 72 + kc * 32 + g * 8]);
                o[0][dj] = mfma16(ap0, bv, o[0][dj]);
                o[1][dj] = mfma16(ap1, bv, o[1][dj]);
            }
        }
        __syncthreads();
    }

    // epilogue: divide by l, write (B,L,E) bf16
    const int b = bh >> 4, h = bh & 15;
#pragma unroll
    for (int mi = 0; mi < 2; ++mi)
#pragma unroll
        for (int r = 0; r < 4; ++r) {
            float inv = 1.0f / lrun[mi][r];
            int row = q0 + mi * 16 + g * 4 + r;
#pragma unroll
            for (int dj = 0; dj < 4; ++dj) {
                int e = h * 64 + dj * 16 + cc;
                Ob[((size_t)b * 2048 + row) * 1024 + e] = f2bf(o[mi][dj][r] * inv);
            }
        }
}

extern "C" void kernel_launch(void* const* d_in, const int* in_sizes, int n_in,
                              void* d_out, int out_size, void* d_ws, size_t ws_size,
                              hipStream_t stream) {
    const float* query = (const float*)d_in[0];
    const float* key   = (const float*)d_in[1];
    const float* value = (const float*)d_in[2];
    const float* Wq = (const float*)d_in[3];
    const float* bq = (const float*)d_in[4];
    const float* Wk = (const float*)d_in[5];
    const float* bk = (const float*)d_in[6];
    const float* Wv = (const float*)d_in[7];
    const float* bv = (const float*)d_in[8];
    const float* Wo = (const float*)d_in[9];
    const float* bo = (const float*)d_in[10];

    // workspace layout (~120.5 MB)
    unsigned short* xq = (unsigned short*)d_ws;      // 8192*1024
    unsigned short* xk = xq + 8388608;
    unsigned short* xv = xk + 8388608;
    unsigned short* wq = xv + 8388608;               // 1024*1024 each
    unsigned short* wk = wq + 1048576;
    unsigned short* wv = wk + 1048576;
    unsigned short* wo = wv + 1048576;
    unsigned short* Qb = wo + 1048576;               // (B*H, L, 64)
    unsigned short* Kb = Qb + 8388608;
    unsigned short* Vb = Kb + 8388608;
    unsigned short* Ob = Vb + 8388608;               // (B, L, E)
    float* biask = (float*)(Ob + 8388608);           // 131072 f32

    k_cvt<<<2048, 256, 0, stream>>>(query, xq, 8388608);
    k_cvt<<<2048, 256, 0, stream>>>(key,   xk, 8388608);
    k_cvt<<<2048, 256, 0, stream>>>(value, xv, 8388608);
    k_cvt<<<512, 256, 0, stream>>>(Wq, wq, 1048576);
    k_cvt<<<512, 256, 0, stream>>>(Wk, wk, 1048576);
    k_cvt<<<512, 256, 0, stream>>>(Wv, wv, 1048576);
    k_cvt<<<512, 256, 0, stream>>>(Wo, wo, 1048576);

    dim3 gg(1024 / 128, 8192 / 128);
    k_gemm<0><<<gg, 256, 0, stream>>>(xq, wq, bq, Qb, 8192, 1024, 1024);
    k_gemm<0><<<gg, 256, 0, stream>>>(xk, wk, bk, Kb, 8192, 1024, 1024);
    k_gemm<0><<<gg, 256, 0, stream>>>(xv, wv, bv, Vb, 8192, 1024, 1024);

    k_rowsq<<<512, 256, 0, stream>>>(Kb, biask, 131072);

    k_attn<<<dim3(16, 64), 256, 0, stream>>>(Qb, Kb, Vb, biask, Ob);

    k_gemm<1><<<gg, 256, 0, stream>>>(Ob, wo, bo, d_out, 8192, 1024, 1024);
}

// Round 3
// 281.953 us; speedup vs baseline: 1.5515x; 1.5515x over previous
//
#include <hip/hip_runtime.h>
#include <hip/hip_bf16.h>
#include <stdint.h>

#define DEV __device__ __forceinline__

typedef __attribute__((ext_vector_type(8))) __bf16 bf16x8;
typedef __attribute__((ext_vector_type(4))) float f32x4;
typedef __attribute__((ext_vector_type(16))) float f32x16;
typedef __attribute__((ext_vector_type(4))) unsigned int u32x4;

#define LOG2E 1.44269504088896f

DEV unsigned short f2bf(float f) {
    union { float f; unsigned int u; } v; v.f = f;
    unsigned int u = v.u;
    return (unsigned short)((u + 0x7FFFu + ((u >> 16) & 1u)) >> 16);
}

DEV f32x4 mfma16(bf16x8 a, bf16x8 b, f32x4 c) {
    return __builtin_amdgcn_mfma_f32_16x16x32_bf16(a, b, c, 0, 0, 0);
}
DEV f32x16 mfma32(bf16x8 a, bf16x8 b, f32x16 c) {
    return __builtin_amdgcn_mfma_f32_32x32x16_bf16(a, b, c, 0, 0, 0);
}
DEV float exp2a(float x) { float r; asm("v_exp_f32 %0, %1" : "=v"(r) : "v"(x)); return r; }
DEV unsigned cvtpk(float lo, float hi) {
    unsigned r; asm("v_cvt_pk_bf16_f32 %0, %1, %2" : "=v"(r) : "v"(lo), "v"(hi)); return r;
}

#define GLOAD_LDS16(g, l)                                                          \
    __builtin_amdgcn_global_load_lds((__attribute__((address_space(1))) void*)(g), \
                                     (__attribute__((address_space(3))) void*)(l), \
                                     16, 0, 0)
#define GLOAD_LDS4(g, l)                                                           \
    __builtin_amdgcn_global_load_lds((__attribute__((address_space(1))) void*)(g), \
                                     (__attribute__((address_space(3))) void*)(l), \
                                     4, 0, 0)

// ---------------- f32 -> bf16 convert (optional scale) ----------------
__global__ void k_cvt(const float* __restrict__ in, unsigned short* __restrict__ out, int n,
                      float scale) {
    int stride = gridDim.x * blockDim.x;
    for (int i = blockIdx.x * blockDim.x + threadIdx.x; i * 4 < n; i += stride) {
        float4 f = reinterpret_cast<const float4*>(in)[i];
        ushort4 o;
        o.x = f2bf(f.x * scale); o.y = f2bf(f.y * scale);
        o.z = f2bf(f.z * scale); o.w = f2bf(f.w * scale);
        reinterpret_cast<ushort4*>(out)[i] = o;
    }
}

// ---------------- bias_k = -0.5*log2e * sum_d k^2 ----------------
__global__ void k_rowsq(const unsigned short* __restrict__ Kp, float* __restrict__ biask, int nrows) {
    int r = blockIdx.x * blockDim.x + threadIdx.x;
    if (r >= nrows) return;
    const unsigned short* p = Kp + (size_t)r * 64;
    float s = 0.f;
#pragma unroll
    for (int i = 0; i < 8; ++i) {
        u32x4 u = reinterpret_cast<const u32x4*>(p)[i];
        bf16x8 h = __builtin_bit_cast(bf16x8, u);
#pragma unroll
        for (int j = 0; j < 8; ++j) { float f = (float)h[j]; s += f * f; }
    }
    biask[r] = -0.5f * LOG2E * s;
}

// ---------------- GEMM: C = A(MxK) * Bw(NxK)^T + bias*bscale ----------------
template <int MODE>
__global__ __launch_bounds__(256) void k_gemm(const unsigned short* __restrict__ A,
                                              const unsigned short* __restrict__ Bw,
                                              const float* __restrict__ bias, float bscale,
                                              void* __restrict__ out,
                                              int M, int N, int K) {
    __shared__ __align__(16) unsigned short As[128 * 64];
    __shared__ __align__(16) unsigned short Bs[128 * 64];
    const int tid = threadIdx.x;
    const int lane = tid & 63, w = tid >> 6;
    const int g = lane >> 4, cc = lane & 15;
    const int wm = w >> 1, wn = w & 1;
    const int bm = blockIdx.y, bn = blockIdx.x;

    f32x4 acc[4][4] = {};
    const int srow = lane >> 3;
    const int scol = (lane & 7) * 8;

    for (int kt = 0; kt < K; kt += 64) {
#pragma unroll
        for (int p = 0; p < 4; ++p) {
            int c = w * 4 + p;
            int row = c * 8 + srow;
            const unsigned short* gA = A + (size_t)(bm * 128 + row) * K + kt + scol;
            GLOAD_LDS16(gA, &As[c * 512]);
            const unsigned short* gB = Bw + (size_t)(bn * 128 + row) * K + kt + scol;
            GLOAD_LDS16(gB, &Bs[c * 512]);
        }
        __syncthreads();
#pragma unroll
        for (int kc = 0; kc < 2; ++kc) {
            bf16x8 af[4], bf[4];
#pragma unroll
            for (int i = 0; i < 4; ++i) {
                af[i] = *reinterpret_cast<const bf16x8*>(&As[(wm * 64 + i * 16 + cc) * 64 + kc * 32 + g * 8]);
                bf[i] = *reinterpret_cast<const bf16x8*>(&Bs[(wn * 64 + i * 16 + cc) * 64 + kc * 32 + g * 8]);
            }
#pragma unroll
            for (int mi = 0; mi < 4; ++mi)
#pragma unroll
                for (int nj = 0; nj < 4; ++nj)
                    acc[mi][nj] = mfma16(af[mi], bf[nj], acc[mi][nj]);
        }
        __syncthreads();
    }

#pragma unroll
    for (int mi = 0; mi < 4; ++mi) {
#pragma unroll
        for (int nj = 0; nj < 4; ++nj) {
            int n = bn * 128 + wn * 64 + nj * 16 + cc;
            float bv = bias[n] * bscale;
#pragma unroll
            for (int r = 0; r < 4; ++r) {
                int m = bm * 128 + wm * 64 + mi * 16 + g * 4 + r;
                float vv = acc[mi][nj][r] + bv;
                if (MODE == 0) {
                    int b = m >> 11, l = m & 2047, h = n >> 6, d = n & 63;
                    ((unsigned short*)out)[(((size_t)b * 16 + h) * 2048 + l) * 64 + d] = f2bf(vv);
                } else {
                    ((float*)out)[(size_t)m * N + n] = vv;
                }
            }
        }
    }
}

// ---------------- V transpose: (BH, L, 64) -> (BH, 64, L) ----------------
__global__ __launch_bounds__(256) void k_vt(const unsigned short* __restrict__ Vb,
                                            unsigned short* __restrict__ VbT) {
    __shared__ __align__(16) unsigned short T[64 * 72];
    const int blk = blockIdx.x;
    const int bh = blk >> 5, lt = blk & 31;
    const int tid = threadIdx.x;
    const int rr = tid >> 3, seg = tid & 7;
#pragma unroll
    for (int p = 0; p < 2; ++p) {
        int row = p * 32 + rr;
        const unsigned short* src = Vb + ((size_t)bh * 2048 + lt * 64 + row) * 64 + seg * 8;
        *reinterpret_cast<u32x4*>(&T[row * 72 + seg * 8]) = *reinterpret_cast<const u32x4*>(src);
    }
    __syncthreads();
#pragma unroll
    for (int p = 0; p < 2; ++p) {
        int d = p * 32 + rr;
        union { u32x4 v; unsigned short s[8]; } o;
#pragma unroll
        for (int j = 0; j < 8; ++j) o.s[j] = T[(seg * 8 + j) * 72 + d];
        unsigned short* dst = VbT + ((size_t)bh * 64 + d) * 2048 + lt * 64 + seg * 8;
        *reinterpret_cast<u32x4*>(dst) = o.v;
    }
}

// ---------------- flash attention, swapped-QK^T 32x32 structure ----------------
// Q (BH,L,64) bf16 pre-scaled by log2e; K (BH,L,64) bf16; VT (BH,64,L) bf16;
// biask (BH*L) f32 = -0.5*log2e*||k||^2; Ob (B,L,E) bf16.
__global__ __launch_bounds__(256, 3) void k_attn2(const unsigned short* __restrict__ Q,
                                                  const unsigned short* __restrict__ K,
                                                  const unsigned short* __restrict__ VT,
                                                  const float* __restrict__ biask,
                                                  unsigned short* __restrict__ Ob) {
    // ushort offsets: K0=0, K1=4096, V0=8192, V1=12288, B0=16384, B1=16512 (f32[64] each)
    __shared__ __align__(16) unsigned short SM[16640];
    const int tid = threadIdx.x;
    const int lane = tid & 63, w = tid >> 6;
    const int l31 = lane & 31, hi = lane >> 5, l7 = lane & 7;
    const int flat = blockIdx.x;
    const int bh = (flat & 7) * 8 + ((flat >> 3) & 7);   // XCD-locality remap (bijective)
    const int qt = flat >> 6;
    const size_t kvbase = (size_t)bh * 2048 * 64;
    const int q0 = qt * 128 + w * 32;

    // Q fragments (B-operand): qf[kc][j] = Q[q0+l31][kc*16 + hi*8 + j]
    bf16x8 qf[4];
#pragma unroll
    for (int kc = 0; kc < 4; ++kc)
        qf[kc] = *reinterpret_cast<const bf16x8*>(Q + kvbase + (size_t)(q0 + l31) * 64 + kc * 16 + hi * 8);

    f32x16 ot[2] = {};
    float mrun = -1e30f, lrun = 0.f;
    const int srow = lane >> 3;

    auto stage = [&](int buf, int t) {
        const int kO = buf ? 4096 : 0;
        const int vO = buf ? 12288 : 8192;
#pragma unroll
        for (int i = 0; i < 2; ++i) {
            int r = w * 16 + i * 8 + srow;
            int cb = l7 ^ (r & 7);   // pre-swizzled source -> linear LDS == swizzled layout
            const unsigned short* gk = K + kvbase + (size_t)(t * 64 + r) * 64 + cb * 8;
            GLOAD_LDS16(gk, &SM[kO + (w * 16 + i * 8) * 64]);
            const unsigned short* gv = VT + kvbase + (size_t)r * 2048 + t * 64 + cb * 8;
            GLOAD_LDS16(gv, &SM[vO + (w * 16 + i * 8) * 64]);
        }
        if (w == 0) {
            const float* gb = biask + bh * 2048 + t * 64 + lane;
            GLOAD_LDS4(gb, &SM[buf ? 16512 : 16384]);
        }
    };

    stage(0, 0);
    int cur = 0;
    for (int t = 0; t < 32; ++t) {
        __syncthreads();
        if (t + 1 < 32) stage(cur ^ 1, t + 1);
        const int kO = cur ? 4096 : 0;
        const int vO = cur ? 12288 : 8192;
        const float* Bl = reinterpret_cast<const float*>(&SM[cur ? 16512 : 16384]);

        // S^T accumulators initialized with key bias (k = t2*32 + (r&3)+8*(r>>2)+4*hi)
        f32x16 st[2];
#pragma unroll
        for (int t2 = 0; t2 < 2; ++t2)
#pragma unroll
            for (int g2 = 0; g2 < 4; ++g2) {
                f32x4 b = *reinterpret_cast<const f32x4*>(Bl + t2 * 32 + g2 * 8 + hi * 4);
#pragma unroll
                for (int j = 0; j < 4; ++j) st[t2][g2 * 4 + j] = b[j];
            }

        // S^T = K * Q^T
#pragma unroll
        for (int kc = 0; kc < 4; ++kc)
#pragma unroll
            for (int t2 = 0; t2 < 2; ++t2) {
                bf16x8 kf = *reinterpret_cast<const bf16x8*>(
                    &SM[kO + (t2 * 32 + l31) * 64 + ((((kc << 1) | hi) ^ l7) << 3)]);
                st[t2] = mfma32(kf, qf[kc], st[t2]);
            }

        // lane-local row max (q = l31), + partner half via shfl
        float a0 = -1e30f, a1 = -1e30f, a2 = -1e30f, a3 = -1e30f;
#pragma unroll
        for (int i = 0; i < 4; ++i) {
            a0 = fmaxf(a0, fmaxf(st[0][i * 4], st[0][i * 4 + 1]));
            a1 = fmaxf(a1, fmaxf(st[0][i * 4 + 2], st[0][i * 4 + 3]));
            a2 = fmaxf(a2, fmaxf(st[1][i * 4], st[1][i * 4 + 1]));
            a3 = fmaxf(a3, fmaxf(st[1][i * 4 + 2], st[1][i * 4 + 3]));
        }
        float mx = fmaxf(fmaxf(a0, a1), fmaxf(a2, a3));
        mx = fmaxf(mx, __shfl_xor(mx, 32));
        float mn = fmaxf(mrun, mx);
        float sc = exp2a(mrun - mn);
        mrun = mn;

        float r0 = 0.f, r1 = 0.f;
#pragma unroll
        for (int i = 0; i < 16; ++i) {
            float p0 = exp2a(st[0][i] - mn); st[0][i] = p0; r0 += p0;
            float p1 = exp2a(st[1][i] - mn); st[1][i] = p1; r1 += p1;
        }
        float rs = r0 + r1;
        rs += __shfl_xor(rs, 32);
        lrun = lrun * sc + rs;
#pragma unroll
        for (int i = 0; i < 16; ++i) { ot[0][i] *= sc; ot[1][i] *= sc; }

        // P^T -> bf16 B-frags. Lane holds P^T[key=(reg&3)+8*(reg>>2)+4*hi + 32*t2][q=l31].
        // B-frag f_kb needs elem j = P^T[kb*16 + hi*8 + j][l31]; missing keys live in the
        // hi-partner lane -> __shfl_xor(...,32) + per-half select (unambiguous semantics).
#pragma unroll
        for (int t2 = 0; t2 < 2; ++t2) {
            unsigned w0 = cvtpk(st[t2][0], st[t2][1]);     // keys (0,1)+4hi
            unsigned w1 = cvtpk(st[t2][2], st[t2][3]);     // keys (2,3)+4hi
            unsigned w2 = cvtpk(st[t2][4], st[t2][5]);     // keys (8,9)+4hi
            unsigned w3 = cvtpk(st[t2][6], st[t2][7]);     // keys (10,11)+4hi
            unsigned w4 = cvtpk(st[t2][8], st[t2][9]);     // keys (16,17)+4hi
            unsigned w5 = cvtpk(st[t2][10], st[t2][11]);   // keys (18,19)+4hi
            unsigned w6 = cvtpk(st[t2][12], st[t2][13]);   // keys (24,25)+4hi
            unsigned w7 = cvtpk(st[t2][14], st[t2][15]);   // keys (26,27)+4hi
            unsigned s0 = __shfl_xor(w0, 32), s1 = __shfl_xor(w1, 32);
            unsigned s2 = __shfl_xor(w2, 32), s3 = __shfl_xor(w3, 32);
            unsigned s4 = __shfl_xor(w4, 32), s5 = __shfl_xor(w5, 32);
            unsigned s6 = __shfl_xor(w6, 32), s7 = __shfl_xor(w7, 32);
            u32x4 p0, p1;
            p0[0] = hi ? s2 : w0;  p0[1] = hi ? s3 : w1;
            p0[2] = hi ? w2 : s0;  p0[3] = hi ? w3 : s1;
            p1[0] = hi ? s6 : w4;  p1[1] = hi ? s7 : w5;
            p1[2] = hi ? w6 : s4;  p1[3] = hi ? w7 : s5;
            bf16x8 f0 = __builtin_bit_cast(bf16x8, p0);
            bf16x8 f1 = __builtin_bit_cast(bf16x8, p1);
            const int kb0 = t2 * 2, kb1 = t2 * 2 + 1;
#pragma unroll
            for (int dj = 0; dj < 2; ++dj) {
                bf16x8 v0 = *reinterpret_cast<const bf16x8*>(
                    &SM[vO + (dj * 32 + l31) * 64 + ((((kb0 << 1) | hi) ^ l7) << 3)]);
                ot[dj] = mfma32(v0, f0, ot[dj]);
                bf16x8 v1 = *reinterpret_cast<const bf16x8*>(
                    &SM[vO + (dj * 32 + l31) * 64 + ((((kb1 << 1) | hi) ^ l7) << 3)]);
                ot[dj] = mfma32(v1, f1, ot[dj]);
            }
        }
        cur ^= 1;
    }

    __syncthreads();
    // epilogue: O^T -> LDS [q][d] (padded 72) -> coalesced global store
    float inv = 1.0f / lrun;
    {
        const int base = (w * 32 + l31) * 72;
#pragma unroll
        for (int dj = 0; dj < 2; ++dj)
#pragma unroll
            for (int i = 0; i < 8; ++i) {
                unsigned pr = cvtpk(ot[dj][2 * i] * inv, ot[dj][2 * i + 1] * inv);
                int d0 = dj * 32 + 2 * (i & 1) + 8 * (i >> 1) + 4 * hi;
                *reinterpret_cast<unsigned*>(&SM[base + d0]) = pr;
            }
    }
    __syncthreads();
    const int b = bh >> 4, h = bh & 15;
#pragma unroll
    for (int pass = 0; pass < 4; ++pass) {
        int row = pass * 32 + (tid >> 3);
        int seg = tid & 7;
        u32x4 vdat = *reinterpret_cast<const u32x4*>(&SM[row * 72 + seg * 8]);
        int l = qt * 128 + row;
        *reinterpret_cast<u32x4*>(Ob + ((size_t)b * 2048 + l) * 1024 + h * 64 + seg * 8) = vdat;
    }
}

extern "C" void kernel_launch(void* const* d_in, const int* in_sizes, int n_in,
                              void* d_out, int out_size, void* d_ws, size_t ws_size,
                              hipStream_t stream) {
    const float* query = (const float*)d_in[0];
    const float* key   = (const float*)d_in[1];
    const float* value = (const float*)d_in[2];
    const float* Wq = (const float*)d_in[3];
    const float* bq = (const float*)d_in[4];
    const float* Wk = (const float*)d_in[5];
    const float* bk = (const float*)d_in[6];
    const float* Wv = (const float*)d_in[7];
    const float* bv = (const float*)d_in[8];
    const float* Wo = (const float*)d_in[9];
    const float* bo = (const float*)d_in[10];

    unsigned short* xq = (unsigned short*)d_ws;      // 8192*1024
    unsigned short* xk = xq + 8388608;
    unsigned short* xv = xk + 8388608;               // reused as VbT after V-GEMM
    unsigned short* wq = xv + 8388608;
    unsigned short* wk = wq + 1048576;
    unsigned short* wv = wk + 1048576;
    unsigned short* wo = wv + 1048576;
    unsigned short* Qb = wo + 1048576;               // (B*H, L, 64)
    unsigned short* Kb = Qb + 8388608;
    unsigned short* Vb = Kb + 8388608;
    unsigned short* Ob = Vb + 8388608;               // (B, L, E)
    float* biask = (float*)(Ob + 8388608);           // 131072 f32
    unsigned short* VbT = xv;                        // (B*H, 64, L)

    k_cvt<<<2048, 256, 0, stream>>>(query, xq, 8388608, 1.0f);
    k_cvt<<<2048, 256, 0, stream>>>(key,   xk, 8388608, 1.0f);
    k_cvt<<<2048, 256, 0, stream>>>(value, xv, 8388608, 1.0f);
    k_cvt<<<512, 256, 0, stream>>>(Wq, wq, 1048576, LOG2E);  // fold log2e into Q
    k_cvt<<<512, 256, 0, stream>>>(Wk, wk, 1048576, 1.0f);
    k_cvt<<<512, 256, 0, stream>>>(Wv, wv, 1048576, 1.0f);
    k_cvt<<<512, 256, 0, stream>>>(Wo, wo, 1048576, 1.0f);

    dim3 gg(1024 / 128, 8192 / 128);
    k_gemm<0><<<gg, 256, 0, stream>>>(xq, wq, bq, LOG2E, Qb, 8192, 1024, 1024);
    k_gemm<0><<<gg, 256, 0, stream>>>(xk, wk, bk, 1.0f, Kb, 8192, 1024, 1024);
    k_gemm<0><<<gg, 256, 0, stream>>>(xv, wv, bv, 1.0f, Vb, 8192, 1024, 1024);

    k_rowsq<<<512, 256, 0, stream>>>(Kb, biask, 131072);
    k_vt<<<2048, 256, 0, stream>>>(Vb, VbT);

    k_attn2<<<1024, 256, 0, stream>>>(Qb, Kb, VbT, biask, Ob);

    k_gemm<1><<<gg, 256, 0, stream>>>(Ob, wo, bo, 1.0f, d_out, 8192, 1024, 1024);
}

// Round 4
// 266.191 us; speedup vs baseline: 1.6434x; 1.0592x over previous
//
#include <hip/hip_runtime.h>
#include <hip/hip_bf16.h>
#include <stdint.h>

#define DEV __device__ __forceinline__

typedef __attribute__((ext_vector_type(8))) __bf16 bf16x8;
typedef __attribute__((ext_vector_type(4))) float f32x4;
typedef __attribute__((ext_vector_type(16))) float f32x16;
typedef __attribute__((ext_vector_type(4))) unsigned int u32x4;

#define LOG2E 1.44269504088896f

DEV unsigned short f2bf(float f) {
    union { float f; unsigned int u; } v; v.f = f;
    unsigned int u = v.u;
    return (unsigned short)((u + 0x7FFFu + ((u >> 16) & 1u)) >> 16);
}

DEV f32x4 mfma16(bf16x8 a, bf16x8 b, f32x4 c) {
    return __builtin_amdgcn_mfma_f32_16x16x32_bf16(a, b, c, 0, 0, 0);
}
DEV f32x16 mfma32(bf16x8 a, bf16x8 b, f32x16 c) {
    return __builtin_amdgcn_mfma_f32_32x32x16_bf16(a, b, c, 0, 0, 0);
}
DEV float exp2a(float x) { float r; asm("v_exp_f32 %0, %1" : "=v"(r) : "v"(x)); return r; }
DEV unsigned cvtpk(float lo, float hi) {
    unsigned r; asm("v_cvt_pk_bf16_f32 %0, %1, %2" : "=v"(r) : "v"(lo), "v"(hi)); return r;
}

#define GLOAD_LDS16(g, l)                                                          \
    __builtin_amdgcn_global_load_lds((__attribute__((address_space(1))) void*)(g), \
                                     (__attribute__((address_space(3))) void*)(l), \
                                     16, 0, 0)
#define GLOAD_LDS4(g, l)                                                           \
    __builtin_amdgcn_global_load_lds((__attribute__((address_space(1))) void*)(g), \
                                     (__attribute__((address_space(3))) void*)(l), \
                                     4, 0, 0)

// ---------------- f32 -> bf16 converts (merged launches) ----------------
__global__ void k_cvtqkv(const float* __restrict__ q, const float* __restrict__ k,
                         const float* __restrict__ v, unsigned short* __restrict__ oq,
                         unsigned short* __restrict__ ok, unsigned short* __restrict__ ov,
                         int n) {
    const float* in = blockIdx.y == 0 ? q : (blockIdx.y == 1 ? k : v);
    unsigned short* out = blockIdx.y == 0 ? oq : (blockIdx.y == 1 ? ok : ov);
    int stride = gridDim.x * blockDim.x;
    for (int i = blockIdx.x * blockDim.x + threadIdx.x; i * 4 < n; i += stride) {
        float4 f = reinterpret_cast<const float4*>(in)[i];
        ushort4 o;
        o.x = f2bf(f.x); o.y = f2bf(f.y); o.z = f2bf(f.z); o.w = f2bf(f.w);
        reinterpret_cast<ushort4*>(out)[i] = o;
    }
}

__global__ void k_cvtw(const float* __restrict__ w0, const float* __restrict__ w1,
                       const float* __restrict__ w2, const float* __restrict__ w3,
                       unsigned short* __restrict__ o0, unsigned short* __restrict__ o1,
                       unsigned short* __restrict__ o2, unsigned short* __restrict__ o3,
                       int n) {
    int y = blockIdx.y;
    const float* in = y == 0 ? w0 : (y == 1 ? w1 : (y == 2 ? w2 : w3));
    unsigned short* out = y == 0 ? o0 : (y == 1 ? o1 : (y == 2 ? o2 : o3));
    float scale = y == 0 ? LOG2E : 1.0f;   // fold log2e into Wq
    int stride = gridDim.x * blockDim.x;
    for (int i = blockIdx.x * blockDim.x + threadIdx.x; i * 4 < n; i += stride) {
        float4 f = reinterpret_cast<const float4*>(in)[i];
        ushort4 o;
        o.x = f2bf(f.x * scale); o.y = f2bf(f.y * scale);
        o.z = f2bf(f.z * scale); o.w = f2bf(f.w * scale);
        reinterpret_cast<ushort4*>(out)[i] = o;
    }
}

// ---------------- bias_k = -0.5*log2e * sum_d k^2 ----------------
__global__ void k_rowsq(const unsigned short* __restrict__ Kp, float* __restrict__ biask, int nrows) {
    int r = blockIdx.x * blockDim.x + threadIdx.x;
    if (r >= nrows) return;
    const unsigned short* p = Kp + (size_t)r * 64;
    float s = 0.f;
#pragma unroll
    for (int i = 0; i < 8; ++i) {
        u32x4 u = reinterpret_cast<const u32x4*>(p)[i];
        bf16x8 h = __builtin_bit_cast(bf16x8, u);
#pragma unroll
        for (int j = 0; j < 8; ++j) { float f = (float)h[j]; s += f * f; }
    }
    biask[r] = -0.5f * LOG2E * s;
}

// ---------------- GEMM: C = A(MxK) * Bw(NxK)^T + bias*bscale ----------------
template <int MODE>
__global__ __launch_bounds__(256) void k_gemm(const unsigned short* __restrict__ A,
                                              const unsigned short* __restrict__ Bw,
                                              const float* __restrict__ bias, float bscale,
                                              void* __restrict__ out,
                                              int M, int N, int K) {
    __shared__ __align__(16) unsigned short As[128 * 64];
    __shared__ __align__(16) unsigned short Bs[128 * 64];
    const int tid = threadIdx.x;
    const int lane = tid & 63, w = tid >> 6;
    const int g = lane >> 4, cc = lane & 15;
    const int wm = w >> 1, wn = w & 1;
    const int bm = blockIdx.y, bn = blockIdx.x;

    f32x4 acc[4][4] = {};
    const int srow = lane >> 3;
    const int scol = (lane & 7) * 8;

    for (int kt = 0; kt < K; kt += 64) {
#pragma unroll
        for (int p = 0; p < 4; ++p) {
            int c = w * 4 + p;
            int row = c * 8 + srow;
            const unsigned short* gA = A + (size_t)(bm * 128 + row) * K + kt + scol;
            GLOAD_LDS16(gA, &As[c * 512]);
            const unsigned short* gB = Bw + (size_t)(bn * 128 + row) * K + kt + scol;
            GLOAD_LDS16(gB, &Bs[c * 512]);
        }
        __syncthreads();
#pragma unroll
        for (int kc = 0; kc < 2; ++kc) {
            bf16x8 af[4], bf[4];
#pragma unroll
            for (int i = 0; i < 4; ++i) {
                af[i] = *reinterpret_cast<const bf16x8*>(&As[(wm * 64 + i * 16 + cc) * 64 + kc * 32 + g * 8]);
                bf[i] = *reinterpret_cast<const bf16x8*>(&Bs[(wn * 64 + i * 16 + cc) * 64 + kc * 32 + g * 8]);
            }
#pragma unroll
            for (int mi = 0; mi < 4; ++mi)
#pragma unroll
                for (int nj = 0; nj < 4; ++nj)
                    acc[mi][nj] = mfma16(af[mi], bf[nj], acc[mi][nj]);
        }
        __syncthreads();
    }

#pragma unroll
    for (int mi = 0; mi < 4; ++mi) {
#pragma unroll
        for (int nj = 0; nj < 4; ++nj) {
            int n = bn * 128 + wn * 64 + nj * 16 + cc;
            float bv = bias[n] * bscale;
#pragma unroll
            for (int r = 0; r < 4; ++r) {
                int m = bm * 128 + wm * 64 + mi * 16 + g * 4 + r;
                float vv = acc[mi][nj][r] + bv;
                if (MODE == 0) {
                    int b = m >> 11, l = m & 2047, h = n >> 6, d = n & 63;
                    ((unsigned short*)out)[(((size_t)b * 16 + h) * 2048 + l) * 64 + d] = f2bf(vv);
                } else {
                    ((float*)out)[(size_t)m * N + n] = vv;
                }
            }
        }
    }
}

// ---------------- V transpose: (BH, L, 64) -> (BH, 64, L) ----------------
__global__ __launch_bounds__(256) void k_vt(const unsigned short* __restrict__ Vb,
                                            unsigned short* __restrict__ VbT) {
    __shared__ __align__(16) unsigned short T[64 * 72];
    const int blk = blockIdx.x;
    const int bh = blk >> 5, lt = blk & 31;
    const int tid = threadIdx.x;
    const int rr = tid >> 3, seg = tid & 7;
#pragma unroll
    for (int p = 0; p < 2; ++p) {
        int row = p * 32 + rr;
        const unsigned short* src = Vb + ((size_t)bh * 2048 + lt * 64 + row) * 64 + seg * 8;
        *reinterpret_cast<u32x4*>(&T[row * 72 + seg * 8]) = *reinterpret_cast<const u32x4*>(src);
    }
    __syncthreads();
#pragma unroll
    for (int p = 0; p < 2; ++p) {
        int d = p * 32 + rr;
        union { u32x4 v; unsigned short s[8]; } o;
#pragma unroll
        for (int j = 0; j < 8; ++j) o.s[j] = T[(seg * 8 + j) * 72 + d];
        unsigned short* dst = VbT + ((size_t)bh * 64 + d) * 2048 + lt * 64 + seg * 8;
        *reinterpret_cast<u32x4*>(dst) = o.v;
    }
}

// ---------------- flash attention, swapped-QK^T, 64 queries per wave ----------------
// Q (BH,L,64) bf16 pre-scaled by log2e; K (BH,L,64) bf16; VT (BH,64,L) bf16;
// biask (BH*L) f32 = -0.5*log2e*||k||^2; Ob (B,L,E) bf16.
__global__ __launch_bounds__(256, 2) void k_attn3(const unsigned short* __restrict__ Q,
                                                  const unsigned short* __restrict__ K,
                                                  const unsigned short* __restrict__ VT,
                                                  const float* __restrict__ biask,
                                                  unsigned short* __restrict__ Ob) {
    // ushort offsets: K0=0, K1=4096, V0=8192, V1=12288, B0=16384, B1=16512.
    // Epilogue reuses [0, 18432) as 256x72 staging.
    __shared__ __align__(16) unsigned short SM[18432];
    const int tid = threadIdx.x;
    const int lane = tid & 63, w = tid >> 6;
    const int l31 = lane & 31, hi = lane >> 5, l7 = lane & 7;
    const int flat = blockIdx.x;
    const int bh = (flat & 7) * 8 + ((flat >> 3) & 7);   // XCD-locality remap (bijective)
    const int qt = flat >> 6;                            // 0..7 (256 queries per block)
    const size_t kvbase = (size_t)bh * 2048 * 64;
    const int q0 = qt * 256 + w * 64;

    // Q fragments (B-operand), two 32-query sub-blocks per wave
    bf16x8 qf[2][4];
#pragma unroll
    for (int qb = 0; qb < 2; ++qb)
#pragma unroll
        for (int kc = 0; kc < 4; ++kc)
            qf[qb][kc] = *reinterpret_cast<const bf16x8*>(
                Q + kvbase + (size_t)(q0 + qb * 32 + l31) * 64 + kc * 16 + hi * 8);

    f32x16 ot[2][2] = {};
    float mrun[2] = {-1e30f, -1e30f}, lrun[2] = {0.f, 0.f};
    const int srow = lane >> 3;

    auto stage = [&](int buf, int t) {
        const int kO = buf ? 4096 : 0;
        const int vO = buf ? 12288 : 8192;
#pragma unroll
        for (int i = 0; i < 2; ++i) {
            int r = w * 16 + i * 8 + srow;
            int cb = l7 ^ (r & 7);   // pre-swizzled source -> linear LDS == swizzled layout
            const unsigned short* gk = K + kvbase + (size_t)(t * 64 + r) * 64 + cb * 8;
            GLOAD_LDS16(gk, &SM[kO + (w * 16 + i * 8) * 64]);
            const unsigned short* gv = VT + kvbase + (size_t)r * 2048 + t * 64 + cb * 8;
            GLOAD_LDS16(gv, &SM[vO + (w * 16 + i * 8) * 64]);
        }
        if (w == 0) {
            const float* gb = biask + bh * 2048 + t * 64 + lane;
            GLOAD_LDS4(gb, &SM[buf ? 16512 : 16384]);
        }
    };

    stage(0, 0);
    int cur = 0;
    for (int t = 0; t < 32; ++t) {
        __syncthreads();
        if (t + 1 < 32) stage(cur ^ 1, t + 1);
        const int kO = cur ? 4096 : 0;
        const int vO = cur ? 12288 : 8192;
        const float* Bl = reinterpret_cast<const float*>(&SM[cur ? 16512 : 16384]);

        // load key bias once (shared by both qb); k = t2*32 + (r&3)+8*(r>>2)+4*hi
        f32x4 bb[2][4];
#pragma unroll
        for (int t2 = 0; t2 < 2; ++t2)
#pragma unroll
            for (int g2 = 0; g2 < 4; ++g2)
                bb[t2][g2] = *reinterpret_cast<const f32x4*>(Bl + t2 * 32 + g2 * 8 + hi * 4);

        f32x16 st[2][2];
#pragma unroll
        for (int qb = 0; qb < 2; ++qb)
#pragma unroll
            for (int t2 = 0; t2 < 2; ++t2)
#pragma unroll
                for (int g2 = 0; g2 < 4; ++g2)
#pragma unroll
                    for (int j = 0; j < 4; ++j) st[qb][t2][g2 * 4 + j] = bb[t2][g2][j];

        // S^T = K * Q^T : each K-frag read feeds both qb
#pragma unroll
        for (int kc = 0; kc < 4; ++kc)
#pragma unroll
            for (int t2 = 0; t2 < 2; ++t2) {
                bf16x8 kf = *reinterpret_cast<const bf16x8*>(
                    &SM[kO + (t2 * 32 + l31) * 64 + ((((kc << 1) | hi) ^ l7) << 3)]);
                st[0][t2] = mfma32(kf, qf[0][kc], st[0][t2]);
                st[1][t2] = mfma32(kf, qf[1][kc], st[1][t2]);
            }

        // online softmax per qb (lane-local rows, q = l31)
#pragma unroll
        for (int qb = 0; qb < 2; ++qb) {
            float a0 = -1e30f, a1 = -1e30f, a2 = -1e30f, a3 = -1e30f;
#pragma unroll
            for (int i = 0; i < 4; ++i) {
                a0 = fmaxf(a0, fmaxf(st[qb][0][i * 4], st[qb][0][i * 4 + 1]));
                a1 = fmaxf(a1, fmaxf(st[qb][0][i * 4 + 2], st[qb][0][i * 4 + 3]));
                a2 = fmaxf(a2, fmaxf(st[qb][1][i * 4], st[qb][1][i * 4 + 1]));
                a3 = fmaxf(a3, fmaxf(st[qb][1][i * 4 + 2], st[qb][1][i * 4 + 3]));
            }
            float mx = fmaxf(fmaxf(a0, a1), fmaxf(a2, a3));
            mx = fmaxf(mx, __shfl_xor(mx, 32));
            // defer-max (T13): only rescale when some row's max grew past mrun + 8
            if (__ballot(mx > mrun[qb] + 8.0f) != 0ull) {
                float mn = fmaxf(mrun[qb], mx);
                float sc = exp2a(mrun[qb] - mn);
                mrun[qb] = mn;
                lrun[qb] *= sc;
#pragma unroll
                for (int i = 0; i < 16; ++i) { ot[qb][0][i] *= sc; ot[qb][1][i] *= sc; }
            }
            float m0 = mrun[qb];
            float r0 = 0.f, r1 = 0.f;
#pragma unroll
            for (int i = 0; i < 16; ++i) {
                float p0 = exp2a(st[qb][0][i] - m0); st[qb][0][i] = p0; r0 += p0;
                float p1 = exp2a(st[qb][1][i] - m0); st[qb][1][i] = p1; r1 += p1;
            }
            float rs = r0 + r1;
            rs += __shfl_xor(rs, 32);
            lrun[qb] += rs;
        }

        // P^T -> bf16 B-frags (cvtpk + shfl_xor32 + per-half select), then O^T += V^T * P^T
#pragma unroll
        for (int t2 = 0; t2 < 2; ++t2) {
            bf16x8 fA[2], fB[2];
#pragma unroll
            for (int qb = 0; qb < 2; ++qb) {
                unsigned w0 = cvtpk(st[qb][t2][0], st[qb][t2][1]);
                unsigned w1 = cvtpk(st[qb][t2][2], st[qb][t2][3]);
                unsigned w2 = cvtpk(st[qb][t2][4], st[qb][t2][5]);
                unsigned w3 = cvtpk(st[qb][t2][6], st[qb][t2][7]);
                unsigned w4 = cvtpk(st[qb][t2][8], st[qb][t2][9]);
                unsigned w5 = cvtpk(st[qb][t2][10], st[qb][t2][11]);
                unsigned w6 = cvtpk(st[qb][t2][12], st[qb][t2][13]);
                unsigned w7 = cvtpk(st[qb][t2][14], st[qb][t2][15]);
                unsigned s0 = __shfl_xor(w0, 32), s1 = __shfl_xor(w1, 32);
                unsigned s2 = __shfl_xor(w2, 32), s3 = __shfl_xor(w3, 32);
                unsigned s4 = __shfl_xor(w4, 32), s5 = __shfl_xor(w5, 32);
                unsigned s6 = __shfl_xor(w6, 32), s7 = __shfl_xor(w7, 32);
                u32x4 p0, p1;
                p0[0] = hi ? s2 : w0;  p0[1] = hi ? s3 : w1;
                p0[2] = hi ? w2 : s0;  p0[3] = hi ? w3 : s1;
                p1[0] = hi ? s6 : w4;  p1[1] = hi ? s7 : w5;
                p1[2] = hi ? w6 : s4;  p1[3] = hi ? w7 : s5;
                fA[qb] = __builtin_bit_cast(bf16x8, p0);
                fB[qb] = __builtin_bit_cast(bf16x8, p1);
            }
            const int kb0 = t2 * 2, kb1 = t2 * 2 + 1;
#pragma unroll
            for (int dj = 0; dj < 2; ++dj) {
                bf16x8 v0 = *reinterpret_cast<const bf16x8*>(
                    &SM[vO + (dj * 32 + l31) * 64 + ((((kb0 << 1) | hi) ^ l7) << 3)]);
                bf16x8 v1 = *reinterpret_cast<const bf16x8*>(
                    &SM[vO + (dj * 32 + l31) * 64 + ((((kb1 << 1) | hi) ^ l7) << 3)]);
                ot[0][dj] = mfma32(v0, fA[0], ot[0][dj]);
                ot[0][dj] = mfma32(v1, fB[0], ot[0][dj]);
                ot[1][dj] = mfma32(v0, fA[1], ot[1][dj]);
                ot[1][dj] = mfma32(v1, fB[1], ot[1][dj]);
            }
        }
        cur ^= 1;
    }

    __syncthreads();
    // epilogue: O^T -> LDS [256 q][72] -> coalesced global store
#pragma unroll
    for (int qb = 0; qb < 2; ++qb) {
        float inv = 1.0f / lrun[qb];
        const int base = (w * 64 + qb * 32 + l31) * 72;
#pragma unroll
        for (int dj = 0; dj < 2; ++dj)
#pragma unroll
            for (int i = 0; i < 8; ++i) {
                unsigned pr = cvtpk(ot[qb][dj][2 * i] * inv, ot[qb][dj][2 * i + 1] * inv);
                int d0 = dj * 32 + 2 * (i & 1) + 8 * (i >> 1) + 4 * hi;
                *reinterpret_cast<unsigned*>(&SM[base + d0]) = pr;
            }
    }
    __syncthreads();
    const int b = bh >> 4, h = bh & 15;
#pragma unroll
    for (int pass = 0; pass < 8; ++pass) {
        int row = pass * 32 + (tid >> 3);
        int seg = tid & 7;
        u32x4 vdat = *reinterpret_cast<const u32x4*>(&SM[row * 72 + seg * 8]);
        int l = qt * 256 + row;
        *reinterpret_cast<u32x4*>(Ob + ((size_t)b * 2048 + l) * 1024 + h * 64 + seg * 8) = vdat;
    }
}

extern "C" void kernel_launch(void* const* d_in, const int* in_sizes, int n_in,
                              void* d_out, int out_size, void* d_ws, size_t ws_size,
                              hipStream_t stream) {
    const float* query = (const float*)d_in[0];
    const float* key   = (const float*)d_in[1];
    const float* value = (const float*)d_in[2];
    const float* Wq = (const float*)d_in[3];
    const float* bq = (const float*)d_in[4];
    const float* Wk = (const float*)d_in[5];
    const float* bk = (const float*)d_in[6];
    const float* Wv = (const float*)d_in[7];
    const float* bv = (const float*)d_in[8];
    const float* Wo = (const float*)d_in[9];
    const float* bo = (const float*)d_in[10];

    unsigned short* xq = (unsigned short*)d_ws;      // 8192*1024
    unsigned short* xk = xq + 8388608;
    unsigned short* xv = xk + 8388608;               // reused as VbT after V-GEMM
    unsigned short* wq = xv + 8388608;
    unsigned short* wk = wq + 1048576;
    unsigned short* wv = wk + 1048576;
    unsigned short* wo = wv + 1048576;
    unsigned short* Qb = wo + 1048576;               // (B*H, L, 64)
    unsigned short* Kb = Qb + 8388608;
    unsigned short* Vb = Kb + 8388608;
    unsigned short* Ob = Vb + 8388608;               // (B, L, E)
    float* biask = (float*)(Ob + 8388608);           // 131072 f32
    unsigned short* VbT = xv;                        // (B*H, 64, L)

    k_cvtqkv<<<dim3(1024, 3), 256, 0, stream>>>(query, key, value, xq, xk, xv, 8388608);
    k_cvtw<<<dim3(256, 4), 256, 0, stream>>>(Wq, Wk, Wv, Wo, wq, wk, wv, wo, 1048576);

    dim3 gg(1024 / 128, 8192 / 128);
    k_gemm<0><<<gg, 256, 0, stream>>>(xq, wq, bq, LOG2E, Qb, 8192, 1024, 1024);
    k_gemm<0><<<gg, 256, 0, stream>>>(xk, wk, bk, 1.0f, Kb, 8192, 1024, 1024);
    k_gemm<0><<<gg, 256, 0, stream>>>(xv, wv, bv, 1.0f, Vb, 8192, 1024, 1024);

    k_rowsq<<<512, 256, 0, stream>>>(Kb, biask, 131072);
    k_vt<<<2048, 256, 0, stream>>>(Vb, VbT);

    k_attn3<<<512, 256, 0, stream>>>(Qb, Kb, VbT, biask, Ob);

    k_gemm<1><<<gg, 256, 0, stream>>>(Ob, wo, bo, 1.0f, d_out, 8192, 1024, 1024);
}